// Round 2
// baseline (531.401 us; speedup 1.0000x reference)
//
#include <hip/hip_runtime.h>
#include <stdint.h>

#define SEQ    2048
#define HIDDEN 4096
#define NQH    32
#define NKVH   2
#define HD     128
#define QKVN   4608   // (32+4)*128
#define ATTN_N 4096   // 32*128

typedef short bf16x8 __attribute__((ext_vector_type(8)));
typedef float f32x4  __attribute__((ext_vector_type(4)));

#define ASYNC16(gp, lp) __builtin_amdgcn_global_load_lds( \
    (const __attribute__((address_space(1))) void*)(gp),  \
    (__attribute__((address_space(3))) void*)(lp), 16, 0, 0)

#define MFMA16(a, b, c) __builtin_amdgcn_mfma_f32_16x16x32_bf16((a), (b), (c), 0, 0, 0)

__device__ __forceinline__ float bf2f(unsigned short u) {
  union { unsigned int i; float f; } v; v.i = ((unsigned int)u) << 16; return v.f;
}
__device__ __forceinline__ unsigned short f2bf(float f) {
  union { float f; unsigned int i; } v; v.f = f;
  unsigned int r = v.i + 0x7fffu + ((v.i >> 16) & 1u);  // RNE
  return (unsigned short)(r >> 16);
}

// ---- dtype probe: bf16 arrays have sane exponents at every index; fp32 read
// ---- as ushort has uniform-random exponent bits at even indices. flag=1 -> fp32
__global__ void detect_dtype(const unsigned short* __restrict__ hs, int* __restrict__ flag) {
  int bad = 0;
  for (int i = 0; i < 128; i += 2) {
    const int e = (hs[i] >> 7) & 0xFF;
    if (e < 100 || e > 140) bad++;
  }
  *flag = (bad > 16) ? 1 : 0;
}

__global__ void to_bf16_any(const void* __restrict__ in, unsigned short* __restrict__ out,
                            int n4, const int* __restrict__ flag) {
  const int i = blockIdx.x * blockDim.x + threadIdx.x;
  if (i >= n4) return;
  if (*flag) {
    const float4 f = ((const float4*)in)[i];
    ushort4 u; u.x = f2bf(f.x); u.y = f2bf(f.y); u.z = f2bf(f.z); u.w = f2bf(f.w);
    ((ushort4*)out)[i] = u;
  } else {
    ((ushort4*)out)[i] = ((const ushort4*)in)[i];
  }
}

__global__ void to_f32_any(const void* __restrict__ in, float* __restrict__ out,
                           int n4, const int* __restrict__ flag) {
  const int i = blockIdx.x * blockDim.x + threadIdx.x;
  if (i >= n4) return;
  if (*flag) {
    ((float4*)out)[i] = ((const float4*)in)[i];
  } else {
    const ushort4 u = ((const ushort4*)in)[i];
    float4 f; f.x = bf2f(u.x); f.y = bf2f(u.y); f.z = bf2f(u.z); f.w = bf2f(u.w);
    ((float4*)out)[i] = f;
  }
}

// ---- transpose + convert: out[c][r] (bf16) = in[r][c]; in is R x C ----
__global__ void transpose_any(const void* __restrict__ in, unsigned short* __restrict__ out,
                              int R, int C, const int* __restrict__ flag) {
  __shared__ unsigned short t[32][36];
  const int r0 = blockIdx.y * 32, c0 = blockIdx.x * 32;
  const int lr = threadIdx.x >> 3;
  const int lc = (threadIdx.x & 7) << 2;
  unsigned short v0, v1, v2, v3;
  if (*flag) {
    const float4 f = *(const float4*)((const float*)in + (size_t)(r0 + lr) * C + c0 + lc);
    v0 = f2bf(f.x); v1 = f2bf(f.y); v2 = f2bf(f.z); v3 = f2bf(f.w);
  } else {
    const ushort4 u = *(const ushort4*)((const unsigned short*)in + (size_t)(r0 + lr) * C + c0 + lc);
    v0 = u.x; v1 = u.y; v2 = u.z; v3 = u.w;
  }
  t[lr][lc] = v0; t[lr][lc + 1] = v1; t[lr][lc + 2] = v2; t[lr][lc + 3] = v3;
  __syncthreads();
  unsigned short* op = out + (size_t)(c0 + lr) * R + r0 + lc;
  ushort4 w;
  w.x = t[lc][lr]; w.y = t[lc + 1][lr]; w.z = t[lc + 2][lr]; w.w = t[lc + 3][lr];
  *(ushort4*)op = w;
}

// ================= 256x128 2-phase pipelined GEMM (T1+T2+T3+T4+T5) ===========
// C = A(MxK) * Bt(NxK)^T (+bias), bf16 in, fp32 acc.
// 512 thr = 8 waves (4M x 2N), per-wave 64x64 out -> acc[4][4] f32x4.
// BK=64 split into two 32-k halves; LDS chunk layout per buffer:
//   A-kh0(8192e) | B-kh0(4096e) | A-kh1(8192e) | B-kh1(4096e) = 48 KiB, x2 buf.
// Per K-tile, 2 phases; each phase:
//   8 ds_read_b128 (4 A-frags + 4 B-frags) | stage 3 global_load_lds (next tile,
//   same k-half) | s_barrier | setprio(1) 16 MFMA setprio(0) | vmcnt(3) | s_barrier
// vmcnt(3): at every wait exactly the 3 newest loads (the chunk-pair staged this
// phase) may remain in flight; the pair read after the barrier was staged one
// phase earlier and is complete. Last tile: vmcnt(0) at end-ph0, no trailing wait.
// Raw s_barrier (never __syncthreads) so the queue is never drained in-loop.
// LDS bank swizzle: 16B slot s of row r holds global k-chunk s^((r>>1)&3)
// (source-side pre-swizzle, LDS dest linear; BANK_CONFLICT=0 on this HW).
// Grid fill at M=2048: (N/128) x (M/256) = 288 (QKV) / 256 (O) blocks -> full
// machine, vs 144 at the 256^2 shape (round-1 regression root cause).
// XCD-contiguous bid remap (nwg%8==0): each XCD works one M-row of blocks so
// its 2MB A-panel stays L2-resident.
__global__ __launch_bounds__(512, 2)
void gemm_bt_2ph(const unsigned short* __restrict__ A,
                 const unsigned short* __restrict__ Bt,
                 const float* __restrict__ bias,
                 void* __restrict__ C,
                 int M, int N, int K, const int* __restrict__ of32) {
  __shared__ __attribute__((aligned(16))) unsigned short lds[49152];  // 96 KiB
  const int tid  = threadIdx.x;
  const int wave = tid >> 6, lane = tid & 63;
  const int quad = lane >> 4, l16 = lane & 15;

  // XCD-contiguous remap (bijective since nwg % 8 == 0 for our grids)
  const int nwg = gridDim.x * gridDim.y;
  int bid = blockIdx.y * gridDim.x + blockIdx.x;
  bid = (bid & 7) * (nwg >> 3) + (bid >> 3);
  const int bx = bid % gridDim.x, by = bid / gridDim.x;
  const int m0 = by * 256, n0 = bx * 128;

  const int wm = (wave >> 1) * 64, wn = (wave & 1) * 64;

  // staging map: thread covers slot (tid&3) of row (tid>>2); A-chunk round 1
  // adds +128 rows (slot swizzle invariant: (row>>1)&3 unchanged by +128)
  const int srow = tid >> 2;
  const int g8   = (((tid & 3) ^ ((srow >> 1) & 3)) << 3);
  const unsigned short* gA = A  + (size_t)(m0 + srow) * K + g8;
  const unsigned short* gB = Bt + (size_t)(n0 + srow) * K + g8;
  const size_t rstep = (size_t)128 * K;

  // frag-read swizzled slot: row = base16 + l16 -> ((row>>1)&3) == ((l16>>1)&3)
  const int rsw   = ((quad ^ ((l16 >> 1) & 3)) << 3);
  const int aBase = (wm + l16) * 32 + rsw;
  const int bBase = 8192 + (wn + l16) * 32 + rsw;

  f32x4 acc[4][4] = {};
  const int nt = K >> 6;

#define STAGEA(bufb, kh, kb) do {                                              \
    const unsigned short* _s = gA + (kb) + ((kh) << 5);                        \
    unsigned short* _d = &lds[(bufb) * 24576 + (kh) * 12288 + tid * 8];        \
    ASYNC16(_s, _d);                                                           \
    ASYNC16(_s + rstep, _d + 4096);                                            \
  } while (0)
#define STAGEB(bufb, kh, kb) do {                                              \
    const unsigned short* _s = gB + (kb) + ((kh) << 5);                        \
    unsigned short* _d = &lds[(bufb) * 24576 + (kh) * 12288 + 8192 + tid * 8]; \
    ASYNC16(_s, _d);                                                           \
  } while (0)
#define BARX() do { asm volatile("" ::: "memory");          \
    __builtin_amdgcn_s_barrier();                           \
    asm volatile("" ::: "memory"); } while (0)

  // prologue: both chunk-pairs of tile 0; pair kh0 must be complete (vmcnt(3))
  STAGEA(0, 0, 0); STAGEB(0, 0, 0);
  STAGEA(0, 1, 0); STAGEB(0, 1, 0);
  asm volatile("s_waitcnt vmcnt(3)" ::: "memory");
  BARX();

  for (int t = 0; t < nt; ++t) {
    const int b = t & 1, nb = b ^ 1;
    const int kb1 = (t + 1) << 6;
    const bool pf = (t + 1 < nt);

    // ---------------- phase 0: k-half 0 ----------------
    {
      const int cb = b * 24576;
      bf16x8 af[4], bfr[4];
#pragma unroll
      for (int i = 0; i < 4; i++) af[i]  = *(const bf16x8*)&lds[cb + aBase + i * 512];
#pragma unroll
      for (int j = 0; j < 4; j++) bfr[j] = *(const bf16x8*)&lds[cb + bBase + j * 512];
      if (pf) { STAGEA(nb, 0, kb1); STAGEB(nb, 0, kb1); }
      BARX();
      __builtin_amdgcn_s_setprio(1);
#pragma unroll
      for (int i = 0; i < 4; i++)
#pragma unroll
        for (int j = 0; j < 4; j++) acc[i][j] = MFMA16(af[i], bfr[j], acc[i][j]);
      __builtin_amdgcn_s_setprio(0);
      if (pf) asm volatile("s_waitcnt vmcnt(3)" ::: "memory");
      else    asm volatile("s_waitcnt vmcnt(0)" ::: "memory");
      BARX();
    }

    // ---------------- phase 1: k-half 1 ----------------
    {
      const int cb = b * 24576 + 12288;
      bf16x8 af[4], bfr[4];
#pragma unroll
      for (int i = 0; i < 4; i++) af[i]  = *(const bf16x8*)&lds[cb + aBase + i * 512];
#pragma unroll
      for (int j = 0; j < 4; j++) bfr[j] = *(const bf16x8*)&lds[cb + bBase + j * 512];
      if (pf) { STAGEA(nb, 1, kb1); STAGEB(nb, 1, kb1); }
      BARX();
      __builtin_amdgcn_s_setprio(1);
#pragma unroll
      for (int i = 0; i < 4; i++)
#pragma unroll
        for (int j = 0; j < 4; j++) acc[i][j] = MFMA16(af[i], bfr[j], acc[i][j]);
      __builtin_amdgcn_s_setprio(0);
      if (pf) {
        asm volatile("s_waitcnt vmcnt(3)" ::: "memory");
        BARX();
      }
    }
  }
#undef STAGEA
#undef STAGEB
#undef BARX

  const int wf32 = of32 ? *of32 : 0;
#pragma unroll
  for (int j = 0; j < 4; j++) {
    const int col = n0 + wn + j * 16 + l16;
    const float bv = bias ? bias[col] : 0.0f;
#pragma unroll
    for (int i = 0; i < 4; i++) {
#pragma unroll
      for (int r = 0; r < 4; r++) {
        const int row = m0 + wm + i * 16 + quad * 4 + r;  // C/D: row=quad*4+reg, col=l16
        const float v = acc[i][j][r] + bv;
        const size_t off = (size_t)row * N + col;
        if (wf32) ((float*)C)[off] = v;
        else      ((unsigned short*)C)[off] = f2bf(v);
      }
    }
  }
}

// --------- RoPE (interleaved) + split into Q (scaled), K, V^T buffers ---------
__global__ void rope_split(const unsigned short* __restrict__ qkv,
                           const float* __restrict__ cosb,
                           const float* __restrict__ sinb,
                           unsigned short* __restrict__ qb,
                           unsigned short* __restrict__ kb,
                           unsigned short* __restrict__ vtb) {
  const int s = blockIdx.x;
  const unsigned short* row = qkv + (size_t)s * QKVN;
  const float sc = 0.08838834764831845f * 1.44269504088896341f;  // 1/sqrt(128)*log2(e)
  for (int p = threadIdx.x; p < QKVN / 2; p += blockDim.x) {
    const int col = p << 1;
    const int head = col >> 7;
    const int d = col & 127;
    float x0 = bf2f(row[col]), x1 = bf2f(row[col + 1]);
    float y0 = x0, y1 = x1;
    if (d < 64) {
      const float c  = cosb[s * 64 + (d >> 1)];
      const float sn = sinb[s * 64 + (d >> 1)];
      y0 = x0 * c - x1 * sn;
      y1 = x1 * c + x0 * sn;
    }
    if (head < NQH) {
      const size_t o = (size_t)head * SEQ * HD + (size_t)s * HD + d;
      qb[o] = f2bf(y0 * sc); qb[o + 1] = f2bf(y1 * sc);
    } else if (head < NQH + NKVH) {
      const size_t o = (size_t)(head - NQH) * SEQ * HD + (size_t)s * HD + d;
      kb[o] = f2bf(y0); kb[o + 1] = f2bf(y1);
    } else {
      const size_t o = (size_t)(head - NQH - NKVH) * HD * SEQ + (size_t)d * SEQ + s;
      vtb[o] = f2bf(x0); vtb[o + SEQ] = f2bf(x1);  // V: no rope, transposed
    }
  }
}

// ------------------- causal flash attention, bf16 MFMA ------------------------
// grid (32 heads, 32 q-tiles of 64 rows), heavy-first. 4 waves/block, 16 rows/wave.
// K/V staged in LDS via global_load_lds with XOR chunk swizzle. Row-sums of P
// computed by an extra MFMA against an all-ones B-frag (replaces shuffle tree).
__global__ __launch_bounds__(256, 3)
void attn_fwd(const unsigned short* __restrict__ qb,
              const unsigned short* __restrict__ kb,
              const unsigned short* __restrict__ vtb,
              unsigned short* __restrict__ ob) {
  const int h = blockIdx.x;
  const int qt = 31 - (int)blockIdx.y;            // heavy-first scheduling
  const int tid = threadIdx.x;
  const int wave = tid >> 6, lane = tid & 63;
  const int quad = lane >> 4, l16 = lane & 15;
  const int q0 = qt * 64 + wave * 16;
  const unsigned short* qh  = qb  + (size_t)h * SEQ * HD;
  const unsigned short* kh  = kb  + (size_t)(h >> 4) * SEQ * HD;
  const unsigned short* vth = vtb + (size_t)(h >> 4) * HD * SEQ;

  __shared__ __attribute__((aligned(16))) unsigned short Ks[64 * 128];   // [key][d], chunk-swizzled
  __shared__ __attribute__((aligned(16))) unsigned short Vs[128 * 64];   // [d][key], chunk-swizzled
  __shared__ __attribute__((aligned(16))) unsigned short plds[4][16][80];

  bf16x8 qf[4];
#pragma unroll
  for (int kbk = 0; kbk < 4; kbk++)   // A-frag: A[m=l16][k=quad*8+j]
    qf[kbk] = *(const bf16x8*)&qh[(size_t)(q0 + l16) * HD + kbk * 32 + quad * 8];

  bf16x8 onesf;
#pragma unroll
  for (int i = 0; i < 8; i++) onesf[i] = (short)0x3F80;   // bf16 1.0

  f32x4 oacc[8] = {};
  f32x4 lacc = {};
  float mrow[4] = {-1e30f, -1e30f, -1e30f, -1e30f};

  for (int kt = 0; kt <= qt; kt++) {
    const int kbase = kt * 64;
    __syncthreads();                   // all waves done reading prev K/V tiles
    // K tile: chunk j of 1024: key=j>>4, LDS slot j&15 holds global chunk (j&15)^(key&15)
#pragma unroll
    for (int c = 0; c < 4; c++) {
      const int j = c * 256 + tid;
      const int key = j >> 4;
      const int g = (j & 15) ^ (key & 15);
      ASYNC16(kh + (size_t)(kbase + key) * HD + g * 8, (unsigned short*)Ks + j * 8);
    }
    // V tile: chunk j of 1024: d=j>>3, slot j&7 holds chunk (j&7)^(d&7)
#pragma unroll
    for (int c = 0; c < 4; c++) {
      const int j = c * 256 + tid;
      const int d = j >> 3;
      const int g = (j & 7) ^ (d & 7);
      ASYNC16(vth + (size_t)d * SEQ + kbase + g * 8, (unsigned short*)Vs + j * 8);
    }
    __syncthreads();                   // vmcnt drained: tiles visible

    f32x4 sv[4] = {};
#pragma unroll
    for (int kbk = 0; kbk < 4; kbk++) {
#pragma unroll
      for (int t = 0; t < 4; t++) {
        bf16x8 kf = *(const bf16x8*)&Ks[(t * 16 + l16) * 128 + (((kbk << 2) + quad) ^ l16) * 8];
        sv[t] = __builtin_amdgcn_mfma_f32_16x16x32_bf16(qf[kbk], kf, sv[t], 0, 0, 0);
      }
    }
    if (kt == qt) {   // diagonal tile masking
#pragma unroll
      for (int t = 0; t < 4; t++) {
        const int key = kbase + t * 16 + l16;
#pragma unroll
        for (int r = 0; r < 4; r++)
          if (key > q0 + quad * 4 + r) sv[t][r] = -1e30f;
      }
    }
    float alpha[4];
#pragma unroll
    for (int r = 0; r < 4; r++) {
      float mx = fmaxf(fmaxf(sv[0][r], sv[1][r]), fmaxf(sv[2][r], sv[3][r]));
#pragma unroll
      for (int off = 8; off; off >>= 1) mx = fmaxf(mx, __shfl_xor(mx, off));
      const float mnew = fmaxf(mrow[r], mx);
      alpha[r] = __builtin_exp2f(mrow[r] - mnew);
      mrow[r] = mnew;
#pragma unroll
      for (int t = 0; t < 4; t++)
        sv[t][r] = __builtin_exp2f(sv[t][r] - mnew);
    }
#pragma unroll
    for (int dt = 0; dt < 8; dt++)
#pragma unroll
      for (int r = 0; r < 4; r++) oacc[dt][r] *= alpha[r];
#pragma unroll
    for (int r = 0; r < 4; r++) lacc[r] *= alpha[r];
    // P: C-layout -> A-layout via LDS round-trip (barriers: uniform trip count)
    __syncthreads();
#pragma unroll
    for (int r = 0; r < 4; r++)
#pragma unroll
      for (int t = 0; t < 4; t++)
        plds[wave][quad * 4 + r][t * 16 + l16] = f2bf(sv[t][r]);
    __syncthreads();
    bf16x8 pf0 = *(const bf16x8*)&plds[wave][l16][quad * 8];
    bf16x8 pf1 = *(const bf16x8*)&plds[wave][l16][32 + quad * 8];
    // row-sum of P via ones B-frag: lacc[r] += sum_k P[row][k] (replicated over l16)
    lacc = __builtin_amdgcn_mfma_f32_16x16x32_bf16(pf0, onesf, lacc, 0, 0, 0);
    lacc = __builtin_amdgcn_mfma_f32_16x16x32_bf16(pf1, onesf, lacc, 0, 0, 0);
#pragma unroll
    for (int dt = 0; dt < 8; dt++) {
      const int vrow = (dt * 16 + l16) * 64;
      bf16x8 vf0 = *(const bf16x8*)&Vs[vrow + ((quad) ^ (l16 & 7)) * 8];
      oacc[dt] = __builtin_amdgcn_mfma_f32_16x16x32_bf16(pf0, vf0, oacc[dt], 0, 0, 0);
      bf16x8 vf1 = *(const bf16x8*)&Vs[vrow + ((4 + quad) ^ (l16 & 7)) * 8];
      oacc[dt] = __builtin_amdgcn_mfma_f32_16x16x32_bf16(pf1, vf1, oacc[dt], 0, 0, 0);
    }
  }
#pragma unroll
  for (int dt = 0; dt < 8; dt++) {
#pragma unroll
    for (int r = 0; r < 4; r++) {
      const float v = oacc[dt][r] / lacc[r];
      ob[(size_t)(q0 + quad * 4 + r) * ATTN_N + h * HD + dt * 16 + l16] = f2bf(v);
    }
  }
}

extern "C" void kernel_launch(void* const* d_in, const int* in_sizes, int n_in,
                              void* d_out, int out_size, void* d_ws, size_t ws_size,
                              hipStream_t stream) {
  const void* hs_raw   = d_in[0];
  const void* cos_raw  = d_in[1];
  const void* sin_raw  = d_in[2];
  const void* wqkv_raw = d_in[3];
  const void* bqkv_raw = d_in[4];
  const void* wo_raw   = d_in[5];
  unsigned short* ws = (unsigned short*)d_ws;

  unsigned short* R1   = ws;                           // wt_qkv -> q/k/vt bufs -> wt_o
  unsigned short* R2   = R1 + (size_t)QKVN * HIDDEN;   // qkv -> attnb
  unsigned short* hs_c = R2 + (size_t)SEQ * QKVN;
  float* cosf  = (float*)(hs_c + (size_t)SEQ * HIDDEN);
  float* sinf  = cosf + SEQ * 64;
  float* biasf = sinf + SEQ * 64;
  int*   flag  = (int*)(biasf + QKVN);

  unsigned short* wt_qkv = R1;
  unsigned short* qbuf   = R1;
  unsigned short* kbuf   = qbuf + (size_t)NQH * SEQ * HD;
  unsigned short* vtbuf  = kbuf + (size_t)NKVH * SEQ * HD;
  unsigned short* wt_o   = R1;
  unsigned short* qkv    = R2;
  unsigned short* attnb  = R2;

  detect_dtype<<<1, 1, 0, stream>>>((const unsigned short*)hs_raw, flag);
  to_bf16_any<<<(SEQ * HIDDEN / 4 + 255) / 256, 256, 0, stream>>>(hs_raw, hs_c, SEQ * HIDDEN / 4, flag);
  to_f32_any<<<(SEQ * 64 / 4 + 255) / 256, 256, 0, stream>>>(cos_raw, cosf, SEQ * 64 / 4, flag);
  to_f32_any<<<(SEQ * 64 / 4 + 255) / 256, 256, 0, stream>>>(sin_raw, sinf, SEQ * 64 / 4, flag);
  to_f32_any<<<(QKVN / 4 + 255) / 256, 256, 0, stream>>>(bqkv_raw, biasf, QKVN / 4, flag);

  transpose_any<<<dim3(QKVN / 32, HIDDEN / 32), 256, 0, stream>>>(wqkv_raw, wt_qkv, HIDDEN, QKVN, flag);
  gemm_bt_2ph<<<dim3(QKVN / 128, SEQ / 256), 512, 0, stream>>>(hs_c, wt_qkv, biasf, qkv, SEQ, QKVN, HIDDEN, nullptr);
  rope_split<<<SEQ, 256, 0, stream>>>(qkv, cosf, sinf, qbuf, kbuf, vtbuf);
  attn_fwd<<<dim3(NQH, SEQ / 64), 256, 0, stream>>>(qbuf, kbuf, vtbuf, attnb);
  transpose_any<<<dim3(ATTN_N / 32, HIDDEN / 32), 256, 0, stream>>>(wo_raw, wt_o, HIDDEN, ATTN_N, flag);
  gemm_bt_2ph<<<dim3(ATTN_N / 128, SEQ / 256), 512, 0, stream>>>(attnb, wt_o, nullptr, d_out, SEQ, ATTN_N, HIDDEN, flag);
}

// Round 3
// 500.375 us; speedup vs baseline: 1.0620x; 1.0620x over previous
//
#include <hip/hip_runtime.h>
#include <stdint.h>

#define SEQ    2048
#define HIDDEN 4096
#define NQH    32
#define NKVH   2
#define HD     128
#define QKVN   4608   // (32+4)*128
#define ATTN_N 4096   // 32*128

typedef short bf16x8 __attribute__((ext_vector_type(8)));
typedef float f32x4  __attribute__((ext_vector_type(4)));

#define ASYNC16(gp, lp) __builtin_amdgcn_global_load_lds( \
    (const __attribute__((address_space(1))) void*)(gp),  \
    (__attribute__((address_space(3))) void*)(lp), 16, 0, 0)

#define MFMA16(a, b, c) __builtin_amdgcn_mfma_f32_16x16x32_bf16((a), (b), (c), 0, 0, 0)

__device__ __forceinline__ float bf2f(unsigned short u) {
  union { unsigned int i; float f; } v; v.i = ((unsigned int)u) << 16; return v.f;
}
__device__ __forceinline__ unsigned short f2bf(float f) {
  union { float f; unsigned int i; } v; v.f = f;
  unsigned int r = v.i + 0x7fffu + ((v.i >> 16) & 1u);  // RNE
  return (unsigned short)(r >> 16);
}

// ---- dtype probe: bf16 arrays have sane exponents at every index; fp32 read
// ---- as ushort has uniform-random exponent bits at even indices. flag=1 -> fp32
__global__ void detect_dtype(const unsigned short* __restrict__ hs, int* __restrict__ flag) {
  int bad = 0;
  for (int i = 0; i < 128; i += 2) {
    const int e = (hs[i] >> 7) & 0xFF;
    if (e < 100 || e > 140) bad++;
  }
  *flag = (bad > 16) ? 1 : 0;
}

__global__ void to_bf16_any(const void* __restrict__ in, unsigned short* __restrict__ out,
                            int n4, const int* __restrict__ flag) {
  const int i = blockIdx.x * blockDim.x + threadIdx.x;
  if (i >= n4) return;
  if (*flag) {
    const float4 f = ((const float4*)in)[i];
    ushort4 u; u.x = f2bf(f.x); u.y = f2bf(f.y); u.z = f2bf(f.z); u.w = f2bf(f.w);
    ((ushort4*)out)[i] = u;
  } else {
    ((ushort4*)out)[i] = ((const ushort4*)in)[i];
  }
}

__global__ void to_f32_any(const void* __restrict__ in, float* __restrict__ out,
                           int n4, const int* __restrict__ flag) {
  const int i = blockIdx.x * blockDim.x + threadIdx.x;
  if (i >= n4) return;
  if (*flag) {
    ((float4*)out)[i] = ((const float4*)in)[i];
  } else {
    const ushort4 u = ((const ushort4*)in)[i];
    float4 f; f.x = bf2f(u.x); f.y = bf2f(u.y); f.z = bf2f(u.z); f.w = bf2f(u.w);
    ((float4*)out)[i] = f;
  }
}

// ---- transpose + convert: out[c][r] (bf16) = in[r][c]; in is R x C ----
__global__ void transpose_any(const void* __restrict__ in, unsigned short* __restrict__ out,
                              int R, int C, const int* __restrict__ flag) {
  __shared__ unsigned short t[32][36];
  const int r0 = blockIdx.y * 32, c0 = blockIdx.x * 32;
  const int lr = threadIdx.x >> 3;
  const int lc = (threadIdx.x & 7) << 2;
  unsigned short v0, v1, v2, v3;
  if (*flag) {
    const float4 f = *(const float4*)((const float*)in + (size_t)(r0 + lr) * C + c0 + lc);
    v0 = f2bf(f.x); v1 = f2bf(f.y); v2 = f2bf(f.z); v3 = f2bf(f.w);
  } else {
    const ushort4 u = *(const ushort4*)((const unsigned short*)in + (size_t)(r0 + lr) * C + c0 + lc);
    v0 = u.x; v1 = u.y; v2 = u.z; v3 = u.w;
  }
  t[lr][lc] = v0; t[lr][lc + 1] = v1; t[lr][lc + 2] = v2; t[lr][lc + 3] = v3;
  __syncthreads();
  unsigned short* op = out + (size_t)(c0 + lr) * R + r0 + lc;
  ushort4 w;
  w.x = t[lc][lr]; w.y = t[lc + 1][lr]; w.z = t[lc + 2][lr]; w.w = t[lc + 3][lr];
  *(ushort4*)op = w;
}

// ========== 256x128 triple-buffered pipelined GEMM, 2 blocks/CU ==============
// C = A(MxK) * Bt(NxK)^T (+bias), bf16 in, fp32 acc.
// 512 thr = 8 waves (4M x 2N), per-wave 64x64 out -> acc[4][4] f32x4.
// BK=32; per buffer: A 256x32 (16KB) | B 128x32 (8KB) = 24KB; 3 buffers = 72KB
// -> 2 blocks/CU co-resident (160/72). Round-2 root cause was 1 block/CU:
// 288 equal blocks = 2 serial rounds = 56% fill. With 2 slots/CU: makespan
// ~1.125x (89% fill) and inter-block MFMA/stage overlap (m114) covers barriers.
// Pipeline: at iter t stage tile t+2 (3 ASYNC16/thread) into the slot vacated
// at iter t-1; end-of-iter vmcnt(3) leaves only tile t+2's loads in flight ->
// tile t+1 is complete before its reads. Drain vmcnt(0) at t>=nt-2 (tile nt-1
// would otherwise be the un-waited newest 3). Raw s_barrier only; overwrite
// hazard safe: slot written at t was read at t-1, reads landed before t-1's
// post-MFMA barrier (lgkmcnt before MFMA), stage issued after that barrier.
// LDS bank swizzle: 16B slot s of row r holds global k-chunk s^((r>>1)&3)
// (source-side pre-swizzle, LDS dest linear; BANK_CONFLICT=0 measured).
// XCD-contiguous bid remap (nwg%8==0 for 288/256 grids): A-panel L2-resident.
__global__ __launch_bounds__(512, 4)
void gemm_bt_p3(const unsigned short* __restrict__ A,
                const unsigned short* __restrict__ Bt,
                const float* __restrict__ bias,
                void* __restrict__ C,
                int M, int N, int K, const int* __restrict__ of32) {
  __shared__ __attribute__((aligned(16))) unsigned short lds[36864];  // 72 KiB
  const int tid  = threadIdx.x;
  const int wave = tid >> 6, lane = tid & 63;
  const int quad = lane >> 4, l16 = lane & 15;

  // XCD-contiguous remap (bijective since nwg % 8 == 0 for our grids)
  const int nwg = gridDim.x * gridDim.y;
  int bid = blockIdx.y * gridDim.x + blockIdx.x;
  bid = (bid & 7) * (nwg >> 3) + (bid >> 3);
  const int bx = bid % gridDim.x, by = bid / gridDim.x;
  const int m0 = by * 256, n0 = bx * 128;

  const int wm = (wave >> 1) * 64, wn = (wave & 1) * 64;

  // staging map: thread covers slot (tid&3) of row (tid>>2); A round 1 adds
  // +128 rows (slot swizzle invariant: (row>>1)&3 unchanged by +128)
  const int srow = tid >> 2;
  const int g8   = (((tid & 3) ^ ((srow >> 1) & 3)) << 3);
  const unsigned short* gA = A  + (size_t)(m0 + srow) * K + g8;
  const unsigned short* gB = Bt + (size_t)(n0 + srow) * K + g8;
  const size_t rstep = (size_t)128 * K;

  // frag-read swizzled slot: row = base16 + l16 -> ((row>>1)&3) == ((l16>>1)&3)
  const int rsw  = ((quad ^ ((l16 >> 1) & 3)) << 3);
  const int aOff = (wm + l16) * 32 + rsw;          // A region: buffer base + 0
  const int bOff = 8192 + (wn + l16) * 32 + rsw;   // B region: buffer base + 8192

  f32x4 acc[4][4] = {};
  const int nt = K >> 5;   // BK = 32

  // one tile stage = 3 loads/thread: A rows 0-127, A rows 128-255, B rows 0-127
#define STAGE(bo, kb) do {                                   \
    unsigned short* _d = &lds[(bo) + tid * 8];               \
    ASYNC16(gA + (kb), _d);                                  \
    ASYNC16(gA + rstep + (kb), _d + 4096);                   \
    ASYNC16(gB + (kb), _d + 8192);                           \
  } while (0)
#define BARX() do { asm volatile("" ::: "memory");          \
    __builtin_amdgcn_s_barrier();                           \
    asm volatile("" ::: "memory"); } while (0)

  // prologue: tiles 0 and 1; tile 0 must be complete (all but newest 3)
  STAGE(0,     0);
  STAGE(12288, 32);
  asm volatile("s_waitcnt vmcnt(3)" ::: "memory");
  BARX();

  int bo0 = 0, bo1 = 12288, bo2 = 24576;
  for (int t = 0; t < nt; ++t) {
    bf16x8 af[4], bfr[4];
#pragma unroll
    for (int i = 0; i < 4; i++) af[i]  = *(const bf16x8*)&lds[bo0 + aOff + i * 512];
#pragma unroll
    for (int j = 0; j < 4; j++) bfr[j] = *(const bf16x8*)&lds[bo0 + bOff + j * 512];
    const bool pf = (t + 2 < nt);
    if (pf) STAGE(bo2, (t + 2) << 5);
    BARX();
    __builtin_amdgcn_s_setprio(1);
#pragma unroll
    for (int i = 0; i < 4; i++)
#pragma unroll
      for (int j = 0; j < 4; j++) acc[i][j] = MFMA16(af[i], bfr[j], acc[i][j]);
    __builtin_amdgcn_s_setprio(0);
    if (pf) asm volatile("s_waitcnt vmcnt(3)" ::: "memory");
    else    asm volatile("s_waitcnt vmcnt(0)" ::: "memory");
    BARX();
    const int tmp = bo0; bo0 = bo1; bo1 = bo2; bo2 = tmp;
  }
#undef STAGE
#undef BARX

  const int wf32 = of32 ? *of32 : 0;
#pragma unroll
  for (int j = 0; j < 4; j++) {
    const int col = n0 + wn + j * 16 + l16;
    const float bv = bias ? bias[col] : 0.0f;
#pragma unroll
    for (int i = 0; i < 4; i++) {
#pragma unroll
      for (int r = 0; r < 4; r++) {
        const int row = m0 + wm + i * 16 + quad * 4 + r;  // C/D: row=quad*4+reg, col=l16
        const float v = acc[i][j][r] + bv;
        const size_t off = (size_t)row * N + col;
        if (wf32) ((float*)C)[off] = v;
        else      ((unsigned short*)C)[off] = f2bf(v);
      }
    }
  }
}

// --------- RoPE (interleaved) + split into Q (scaled), K, V^T buffers ---------
__global__ void rope_split(const unsigned short* __restrict__ qkv,
                           const float* __restrict__ cosb,
                           const float* __restrict__ sinb,
                           unsigned short* __restrict__ qb,
                           unsigned short* __restrict__ kb,
                           unsigned short* __restrict__ vtb) {
  const int s = blockIdx.x;
  const unsigned short* row = qkv + (size_t)s * QKVN;
  const float sc = 0.08838834764831845f * 1.44269504088896341f;  // 1/sqrt(128)*log2(e)
  for (int p = threadIdx.x; p < QKVN / 2; p += blockDim.x) {
    const int col = p << 1;
    const int head = col >> 7;
    const int d = col & 127;
    float x0 = bf2f(row[col]), x1 = bf2f(row[col + 1]);
    float y0 = x0, y1 = x1;
    if (d < 64) {
      const float c  = cosb[s * 64 + (d >> 1)];
      const float sn = sinb[s * 64 + (d >> 1)];
      y0 = x0 * c - x1 * sn;
      y1 = x1 * c + x0 * sn;
    }
    if (head < NQH) {
      const size_t o = (size_t)head * SEQ * HD + (size_t)s * HD + d;
      qb[o] = f2bf(y0 * sc); qb[o + 1] = f2bf(y1 * sc);
    } else if (head < NQH + NKVH) {
      const size_t o = (size_t)(head - NQH) * SEQ * HD + (size_t)s * HD + d;
      kb[o] = f2bf(y0); kb[o + 1] = f2bf(y1);
    } else {
      const size_t o = (size_t)(head - NQH - NKVH) * HD * SEQ + (size_t)d * SEQ + s;
      vtb[o] = f2bf(x0); vtb[o + SEQ] = f2bf(x1);  // V: no rope, transposed
    }
  }
}

// ------------------- causal flash attention, bf16 MFMA ------------------------
// grid (32 heads, 32 q-tiles of 64 rows), heavy-first. 4 waves/block, 16 rows/wave.
// K/V staged in LDS via global_load_lds with XOR chunk swizzle. Row-sums of P
// computed by an extra MFMA against an all-ones B-frag (replaces shuffle tree).
__global__ __launch_bounds__(256, 3)
void attn_fwd(const unsigned short* __restrict__ qb,
              const unsigned short* __restrict__ kb,
              const unsigned short* __restrict__ vtb,
              unsigned short* __restrict__ ob) {
  const int h = blockIdx.x;
  const int qt = 31 - (int)blockIdx.y;            // heavy-first scheduling
  const int tid = threadIdx.x;
  const int wave = tid >> 6, lane = tid & 63;
  const int quad = lane >> 4, l16 = lane & 15;
  const int q0 = qt * 64 + wave * 16;
  const unsigned short* qh  = qb  + (size_t)h * SEQ * HD;
  const unsigned short* kh  = kb  + (size_t)(h >> 4) * SEQ * HD;
  const unsigned short* vth = vtb + (size_t)(h >> 4) * HD * SEQ;

  __shared__ __attribute__((aligned(16))) unsigned short Ks[64 * 128];   // [key][d], chunk-swizzled
  __shared__ __attribute__((aligned(16))) unsigned short Vs[128 * 64];   // [d][key], chunk-swizzled
  __shared__ __attribute__((aligned(16))) unsigned short plds[4][16][80];

  bf16x8 qf[4];
#pragma unroll
  for (int kbk = 0; kbk < 4; kbk++)   // A-frag: A[m=l16][k=quad*8+j]
    qf[kbk] = *(const bf16x8*)&qh[(size_t)(q0 + l16) * HD + kbk * 32 + quad * 8];

  bf16x8 onesf;
#pragma unroll
  for (int i = 0; i < 8; i++) onesf[i] = (short)0x3F80;   // bf16 1.0

  f32x4 oacc[8] = {};
  f32x4 lacc = {};
  float mrow[4] = {-1e30f, -1e30f, -1e30f, -1e30f};

  for (int kt = 0; kt <= qt; kt++) {
    const int kbase = kt * 64;
    __syncthreads();                   // all waves done reading prev K/V tiles
    // K tile: chunk j of 1024: key=j>>4, LDS slot j&15 holds global chunk (j&15)^(key&15)
#pragma unroll
    for (int c = 0; c < 4; c++) {
      const int j = c * 256 + tid;
      const int key = j >> 4;
      const int g = (j & 15) ^ (key & 15);
      ASYNC16(kh + (size_t)(kbase + key) * HD + g * 8, (unsigned short*)Ks + j * 8);
    }
    // V tile: chunk j of 1024: d=j>>3, slot j&7 holds chunk (j&7)^(d&7)
#pragma unroll
    for (int c = 0; c < 4; c++) {
      const int j = c * 256 + tid;
      const int d = j >> 3;
      const int g = (j & 7) ^ (d & 7);
      ASYNC16(vth + (size_t)d * SEQ + kbase + g * 8, (unsigned short*)Vs + j * 8);
    }
    __syncthreads();                   // vmcnt drained: tiles visible

    f32x4 sv[4] = {};
#pragma unroll
    for (int kbk = 0; kbk < 4; kbk++) {
#pragma unroll
      for (int t = 0; t < 4; t++) {
        bf16x8 kf = *(const bf16x8*)&Ks[(t * 16 + l16) * 128 + (((kbk << 2) + quad) ^ l16) * 8];
        sv[t] = __builtin_amdgcn_mfma_f32_16x16x32_bf16(qf[kbk], kf, sv[t], 0, 0, 0);
      }
    }
    if (kt == qt) {   // diagonal tile masking
#pragma unroll
      for (int t = 0; t < 4; t++) {
        const int key = kbase + t * 16 + l16;
#pragma unroll
        for (int r = 0; r < 4; r++)
          if (key > q0 + quad * 4 + r) sv[t][r] = -1e30f;
      }
    }
    float alpha[4];
#pragma unroll
    for (int r = 0; r < 4; r++) {
      float mx = fmaxf(fmaxf(sv[0][r], sv[1][r]), fmaxf(sv[2][r], sv[3][r]));
#pragma unroll
      for (int off = 8; off; off >>= 1) mx = fmaxf(mx, __shfl_xor(mx, off));
      const float mnew = fmaxf(mrow[r], mx);
      alpha[r] = __builtin_exp2f(mrow[r] - mnew);
      mrow[r] = mnew;
#pragma unroll
      for (int t = 0; t < 4; t++)
        sv[t][r] = __builtin_exp2f(sv[t][r] - mnew);
    }
#pragma unroll
    for (int dt = 0; dt < 8; dt++)
#pragma unroll
      for (int r = 0; r < 4; r++) oacc[dt][r] *= alpha[r];
#pragma unroll
    for (int r = 0; r < 4; r++) lacc[r] *= alpha[r];
    // P: C-layout -> A-layout via LDS round-trip (barriers: uniform trip count)
    __syncthreads();
#pragma unroll
    for (int r = 0; r < 4; r++)
#pragma unroll
      for (int t = 0; t < 4; t++)
        plds[wave][quad * 4 + r][t * 16 + l16] = f2bf(sv[t][r]);
    __syncthreads();
    bf16x8 pf0 = *(const bf16x8*)&plds[wave][l16][quad * 8];
    bf16x8 pf1 = *(const bf16x8*)&plds[wave][l16][32 + quad * 8];
    // row-sum of P via ones B-frag: lacc[r] += sum_k P[row][k] (replicated over l16)
    lacc = __builtin_amdgcn_mfma_f32_16x16x32_bf16(pf0, onesf, lacc, 0, 0, 0);
    lacc = __builtin_amdgcn_mfma_f32_16x16x32_bf16(pf1, onesf, lacc, 0, 0, 0);
#pragma unroll
    for (int dt = 0; dt < 8; dt++) {
      const int vrow = (dt * 16 + l16) * 64;
      bf16x8 vf0 = *(const bf16x8*)&Vs[vrow + ((quad) ^ (l16 & 7)) * 8];
      oacc[dt] = __builtin_amdgcn_mfma_f32_16x16x32_bf16(pf0, vf0, oacc[dt], 0, 0, 0);
      bf16x8 vf1 = *(const bf16x8*)&Vs[vrow + ((4 + quad) ^ (l16 & 7)) * 8];
      oacc[dt] = __builtin_amdgcn_mfma_f32_16x16x32_bf16(pf1, vf1, oacc[dt], 0, 0, 0);
    }
  }
#pragma unroll
  for (int dt = 0; dt < 8; dt++) {
#pragma unroll
    for (int r = 0; r < 4; r++) {
      const float v = oacc[dt][r] / lacc[r];
      ob[(size_t)(q0 + quad * 4 + r) * ATTN_N + h * HD + dt * 16 + l16] = f2bf(v);
    }
  }
}

extern "C" void kernel_launch(void* const* d_in, const int* in_sizes, int n_in,
                              void* d_out, int out_size, void* d_ws, size_t ws_size,
                              hipStream_t stream) {
  const void* hs_raw   = d_in[0];
  const void* cos_raw  = d_in[1];
  const void* sin_raw  = d_in[2];
  const void* wqkv_raw = d_in[3];
  const void* bqkv_raw = d_in[4];
  const void* wo_raw   = d_in[5];
  unsigned short* ws = (unsigned short*)d_ws;

  unsigned short* R1   = ws;                           // wt_qkv -> q/k/vt bufs -> wt_o
  unsigned short* R2   = R1 + (size_t)QKVN * HIDDEN;   // qkv -> attnb
  unsigned short* hs_c = R2 + (size_t)SEQ * QKVN;
  float* cosf  = (float*)(hs_c + (size_t)SEQ * HIDDEN);
  float* sinf  = cosf + SEQ * 64;
  float* biasf = sinf + SEQ * 64;
  int*   flag  = (int*)(biasf + QKVN);

  unsigned short* wt_qkv = R1;
  unsigned short* qbuf   = R1;
  unsigned short* kbuf   = qbuf + (size_t)NQH * SEQ * HD;
  unsigned short* vtbuf  = kbuf + (size_t)NKVH * SEQ * HD;
  unsigned short* wt_o   = R1;
  unsigned short* qkv    = R2;
  unsigned short* attnb  = R2;

  detect_dtype<<<1, 1, 0, stream>>>((const unsigned short*)hs_raw, flag);
  to_bf16_any<<<(SEQ * HIDDEN / 4 + 255) / 256, 256, 0, stream>>>(hs_raw, hs_c, SEQ * HIDDEN / 4, flag);
  to_f32_any<<<(SEQ * 64 / 4 + 255) / 256, 256, 0, stream>>>(cos_raw, cosf, SEQ * 64 / 4, flag);
  to_f32_any<<<(SEQ * 64 / 4 + 255) / 256, 256, 0, stream>>>(sin_raw, sinf, SEQ * 64 / 4, flag);
  to_f32_any<<<(QKVN / 4 + 255) / 256, 256, 0, stream>>>(bqkv_raw, biasf, QKVN / 4, flag);

  transpose_any<<<dim3(QKVN / 32, HIDDEN / 32), 256, 0, stream>>>(wqkv_raw, wt_qkv, HIDDEN, QKVN, flag);
  gemm_bt_p3<<<dim3(QKVN / 128, SEQ / 256), 512, 0, stream>>>(hs_c, wt_qkv, biasf, qkv, SEQ, QKVN, HIDDEN, nullptr);
  rope_split<<<SEQ, 256, 0, stream>>>(qkv, cosf, sinf, qbuf, kbuf, vtbuf);
  attn_fwd<<<dim3(NQH, SEQ / 64), 256, 0, stream>>>(qbuf, kbuf, vtbuf, attnb);
  transpose_any<<<dim3(ATTN_N / 32, HIDDEN / 32), 256, 0, stream>>>(wo_raw, wt_o, HIDDEN, ATTN_N, flag);
  gemm_bt_p3<<<dim3(ATTN_N / 128, SEQ / 256), 512, 0, stream>>>(attnb, wt_o, nullptr, d_out, SEQ, ATTN_N, HIDDEN, flag);
}

// Round 4
// 497.423 us; speedup vs baseline: 1.0683x; 1.0059x over previous
//
#include <hip/hip_runtime.h>
#include <stdint.h>

#define SEQ    2048
#define HIDDEN 4096
#define NQH    32
#define NKVH   2
#define HD     128
#define QKVN   4608   // (32+4)*128
#define ATTN_N 4096   // 32*128

typedef short bf16x8 __attribute__((ext_vector_type(8)));
typedef float f32x4  __attribute__((ext_vector_type(4)));

#define ASYNC16(gp, lp) __builtin_amdgcn_global_load_lds( \
    (const __attribute__((address_space(1))) void*)(gp),  \
    (__attribute__((address_space(3))) void*)(lp), 16, 0, 0)

__device__ __forceinline__ float bf2f(unsigned short u) {
  union { unsigned int i; float f; } v; v.i = ((unsigned int)u) << 16; return v.f;
}
__device__ __forceinline__ unsigned short f2bf(float f) {
  union { float f; unsigned int i; } v; v.f = f;
  unsigned int r = v.i + 0x7fffu + ((v.i >> 16) & 1u);  // RNE
  return (unsigned short)(r >> 16);
}

// ---- dtype probe: bf16 arrays have sane exponents at every index; fp32 read
// ---- as ushort has uniform-random exponent bits at even indices. flag=1 -> fp32
__global__ void detect_dtype(const unsigned short* __restrict__ hs, int* __restrict__ flag) {
  int bad = 0;
  for (int i = 0; i < 128; i += 2) {
    const int e = (hs[i] >> 7) & 0xFF;
    if (e < 100 || e > 140) bad++;
  }
  *flag = (bad > 16) ? 1 : 0;
}

__global__ void to_bf16_any(const void* __restrict__ in, unsigned short* __restrict__ out,
                            int n4, const int* __restrict__ flag) {
  const int i = blockIdx.x * blockDim.x + threadIdx.x;
  if (i >= n4) return;
  if (*flag) {
    const float4 f = ((const float4*)in)[i];
    ushort4 u; u.x = f2bf(f.x); u.y = f2bf(f.y); u.z = f2bf(f.z); u.w = f2bf(f.w);
    ((ushort4*)out)[i] = u;
  } else {
    ((ushort4*)out)[i] = ((const ushort4*)in)[i];
  }
}

__global__ void to_f32_any(const void* __restrict__ in, float* __restrict__ out,
                           int n4, const int* __restrict__ flag) {
  const int i = blockIdx.x * blockDim.x + threadIdx.x;
  if (i >= n4) return;
  if (*flag) {
    ((float4*)out)[i] = ((const float4*)in)[i];
  } else {
    const ushort4 u = ((const ushort4*)in)[i];
    float4 f; f.x = bf2f(u.x); f.y = bf2f(u.y); f.z = bf2f(u.z); f.w = bf2f(u.w);
    ((float4*)out)[i] = f;
  }
}

// ---- transpose + convert: out[c][r] (bf16) = in[r][c]; in is R x C ----
__global__ void transpose_any(const void* __restrict__ in, unsigned short* __restrict__ out,
                              int R, int C, const int* __restrict__ flag) {
  __shared__ unsigned short t[32][36];
  const int r0 = blockIdx.y * 32, c0 = blockIdx.x * 32;
  const int lr = threadIdx.x >> 3;
  const int lc = (threadIdx.x & 7) << 2;
  unsigned short v0, v1, v2, v3;
  if (*flag) {
    const float4 f = *(const float4*)((const float*)in + (size_t)(r0 + lr) * C + c0 + lc);
    v0 = f2bf(f.x); v1 = f2bf(f.y); v2 = f2bf(f.z); v3 = f2bf(f.w);
  } else {
    const ushort4 u = *(const ushort4*)((const unsigned short*)in + (size_t)(r0 + lr) * C + c0 + lc);
    v0 = u.x; v1 = u.y; v2 = u.z; v3 = u.w;
  }
  t[lr][lc] = v0; t[lr][lc + 1] = v1; t[lr][lc + 2] = v2; t[lr][lc + 3] = v3;
  __syncthreads();
  unsigned short* op = out + (size_t)(c0 + lr) * R + r0 + lc;
  ushort4 w;
  w.x = t[lc][lr]; w.y = t[lc + 1][lr]; w.z = t[lc + 2][lr]; w.w = t[lc + 3][lr];
  *(ushort4*)op = w;
}

// ------------- C = A(MxK) * Bt(NxK)^T (+bias), bf16 in, fp32 acc --------------
// m97 structure: 128x128 tile, BK=32, async global->LDS staging (width=16).
// Best measured GEMM on this problem (111-113 us, MfmaUtil 28) — rounds 1-3
// schedule variants (8-phase 256^2, 2-phase 256x128, triple-buffer 2-blk/CU)
// all regressed to 120-145 us at these shapes. Keep verbatim.
__global__ __launch_bounds__(256, 2)
void gemm_bt(const unsigned short* __restrict__ A,
             const unsigned short* __restrict__ Bt,
             const float* __restrict__ bias,
             void* __restrict__ C,
             int M, int N, int K, const int* __restrict__ of32) {
  __shared__ __attribute__((aligned(16))) unsigned short As[128 * 32];
  __shared__ __attribute__((aligned(16))) unsigned short Bs[128 * 32];
  const int tid  = threadIdx.x;
  const int wave = tid >> 6, lane = tid & 63;
  const int quad = lane >> 4, l16 = lane & 15;
  const int m0 = blockIdx.y * 128, n0 = blockIdx.x * 128;
  const int wm = (wave >> 1) * 64, wn = (wave & 1) * 64;

  // thread t stages row=t/4, swizzled k-chunk g=(t&3)^((row>>1)&3); LDS = t*16B
  const int crow = tid >> 2;
  const int gsw = ((tid & 3) ^ ((crow >> 1) & 3)) << 3;
  const unsigned short* gA = A + (size_t)(m0 + crow) * K + gsw;
  const unsigned short* gB = Bt + (size_t)(n0 + crow) * K + gsw;
  unsigned short* lA = As + tid * 8;
  unsigned short* lB = Bs + tid * 8;

  // frag-read swizzled chunk offset (elements)
  const int cxor = (quad ^ ((l16 >> 1) & 3)) << 3;

  f32x4 acc[4][4] = {};

  for (int k0 = 0; k0 < K; k0 += 32) {
    __syncthreads();                 // prev iter's LDS reads done
    ASYNC16(gA + k0, lA);
    ASYNC16(gA + (size_t)64 * K + k0, lA + 64 * 32);
    ASYNC16(gB + k0, lB);
    ASYNC16(gB + (size_t)64 * K + k0, lB + 64 * 32);
    __syncthreads();                 // drains vmcnt: tile visible
    bf16x8 aF[4], bF[4];
#pragma unroll
    for (int i = 0; i < 4; i++)
      aF[i] = *(const bf16x8*)&As[(wm + i * 16 + l16) * 32 + cxor];
#pragma unroll
    for (int j = 0; j < 4; j++)
      bF[j] = *(const bf16x8*)&Bs[(wn + j * 16 + l16) * 32 + cxor];
#pragma unroll
    for (int i = 0; i < 4; i++)
#pragma unroll
      for (int j = 0; j < 4; j++)
        acc[i][j] = __builtin_amdgcn_mfma_f32_16x16x32_bf16(aF[i], bF[j], acc[i][j], 0, 0, 0);
  }

  const int wf32 = of32 ? *of32 : 0;
#pragma unroll
  for (int j = 0; j < 4; j++) {
    const int col = n0 + wn + j * 16 + l16;
    const float bv = bias ? bias[col] : 0.0f;
#pragma unroll
    for (int i = 0; i < 4; i++) {
#pragma unroll
      for (int r = 0; r < 4; r++) {
        const int row = m0 + wm + i * 16 + quad * 4 + r;   // C/D: row=quad*4+reg, col=l16
        const float v = acc[i][j][r] + bv;
        const size_t off = (size_t)row * N + col;
        if (wf32) ((float*)C)[off] = v;
        else      ((unsigned short*)C)[off] = f2bf(v);
      }
    }
  }
}

// --------- RoPE (interleaved) + split into Q (scaled), K, V^T buffers ---------
__global__ void rope_split(const unsigned short* __restrict__ qkv,
                           const float* __restrict__ cosb,
                           const float* __restrict__ sinb,
                           unsigned short* __restrict__ qb,
                           unsigned short* __restrict__ kb,
                           unsigned short* __restrict__ vtb) {
  const int s = blockIdx.x;
  const unsigned short* row = qkv + (size_t)s * QKVN;
  const float sc = 0.08838834764831845f * 1.44269504088896341f;  // 1/sqrt(128)*log2(e)
  for (int p = threadIdx.x; p < QKVN / 2; p += blockDim.x) {
    const int col = p << 1;
    const int head = col >> 7;
    const int d = col & 127;
    float x0 = bf2f(row[col]), x1 = bf2f(row[col + 1]);
    float y0 = x0, y1 = x1;
    if (d < 64) {
      const float c  = cosb[s * 64 + (d >> 1)];
      const float sn = sinb[s * 64 + (d >> 1)];
      y0 = x0 * c - x1 * sn;
      y1 = x1 * c + x0 * sn;
    }
    if (head < NQH) {
      const size_t o = (size_t)head * SEQ * HD + (size_t)s * HD + d;
      qb[o] = f2bf(y0 * sc); qb[o + 1] = f2bf(y1 * sc);
    } else if (head < NQH + NKVH) {
      const size_t o = (size_t)(head - NQH) * SEQ * HD + (size_t)s * HD + d;
      kb[o] = f2bf(y0); kb[o + 1] = f2bf(y1);
    } else {
      const size_t o = (size_t)(head - NQH - NKVH) * HD * SEQ + (size_t)d * SEQ + s;
      vtb[o] = f2bf(x0); vtb[o + SEQ] = f2bf(x1);  // V: no rope, transposed
    }
  }
}

// ------------------- causal flash attention, bf16 MFMA ------------------------
// grid (32 heads, 32 q-tiles of 64 rows), heavy-first. 4 waves/block, 16 rows/wave.
// ROUND-4 RESTRUCTURE: double-buffered K/V + single barrier per K-tile.
//  - K/V tiles double-buffered (LDS 74 KiB, 2 blocks/CU). Loop top: ONE
//    __syncthreads (its implicit vmcnt(0) is exactly the wait for the tile
//    staged one full iteration earlier, and it joins all waves so re-staging
//    buf^1 cannot race iter kt-1 readers). THEN issue next tile's 8
//    global_load_lds -> they fly under this tile's entire QK/softmax/PV.
//    Old code: 4 barriers/tile, stage drained immediately (zero overlap).
//  - plds is WAVE-PRIVATE ([wave][..] written/read by same wave only): the
//    two barriers around the P round-trip were unnecessary; intra-wave
//    lgkmcnt ordering (compiler-inserted) suffices. Deleted.
// Row-sums of P via extra MFMA against all-ones B-frag (replaces shuffle tree).
__global__ __launch_bounds__(256, 2)
void attn_fwd(const unsigned short* __restrict__ qb,
              const unsigned short* __restrict__ kb,
              const unsigned short* __restrict__ vtb,
              unsigned short* __restrict__ ob) {
  const int h = blockIdx.x;
  const int qt = 31 - (int)blockIdx.y;            // heavy-first scheduling
  const int tid = threadIdx.x;
  const int wave = tid >> 6, lane = tid & 63;
  const int quad = lane >> 4, l16 = lane & 15;
  const int q0 = qt * 64 + wave * 16;
  const unsigned short* qh  = qb  + (size_t)h * SEQ * HD;
  const unsigned short* kh  = kb  + (size_t)(h >> 4) * SEQ * HD;
  const unsigned short* vth = vtb + (size_t)(h >> 4) * HD * SEQ;

  __shared__ __attribute__((aligned(16))) unsigned short Ks[2][64 * 128];  // [key][d], chunk-swizzled
  __shared__ __attribute__((aligned(16))) unsigned short Vs[2][128 * 64];  // [d][key], chunk-swizzled
  __shared__ __attribute__((aligned(16))) unsigned short plds[4][16][80];  // wave-private

  bf16x8 qf[4];
#pragma unroll
  for (int kbk = 0; kbk < 4; kbk++)   // A-frag: A[m=l16][k=quad*8+j]
    qf[kbk] = *(const bf16x8*)&qh[(size_t)(q0 + l16) * HD + kbk * 32 + quad * 8];

  bf16x8 onesf;
#pragma unroll
  for (int i = 0; i < 8; i++) onesf[i] = (short)0x3F80;   // bf16 1.0

  f32x4 oacc[8] = {};
  f32x4 lacc = {};
  float mrow[4] = {-1e30f, -1e30f, -1e30f, -1e30f};

  // stage tile kt_ into buffer bsel: 8 global_load_lds per thread
  // K tile: chunk j of 1024: key=j>>4, slot j&15 holds global chunk (j&15)^(key&15)
  // V tile: chunk j of 1024: d=j>>3,  slot j&7  holds global chunk (j&7)^(d&7)
#define STAGEKV(kt_, bsel) do {                                                  \
    const int kb_ = (kt_) * 64;                                                  \
    _Pragma("unroll")                                                            \
    for (int c = 0; c < 4; c++) {                                                \
      const int j = c * 256 + tid;                                               \
      const int key = j >> 4;                                                    \
      const int g = (j & 15) ^ (key & 15);                                       \
      ASYNC16(kh + (size_t)(kb_ + key) * HD + g * 8, &Ks[bsel][0] + j * 8);      \
    }                                                                            \
    _Pragma("unroll")                                                            \
    for (int c = 0; c < 4; c++) {                                                \
      const int j = c * 256 + tid;                                               \
      const int d = j >> 3;                                                      \
      const int g = (j & 7) ^ (d & 7);                                           \
      ASYNC16(vth + (size_t)d * SEQ + kb_ + g * 8, &Vs[bsel][0] + j * 8);        \
    }                                                                            \
  } while (0)

  STAGEKV(0, 0);

  for (int kt = 0; kt <= qt; kt++) {
    const int b = kt & 1;
    const int kbase = kt * 64;
    __syncthreads();                   // drains vmcnt: tile kt visible to all;
                                       // all waves done with iter kt-1 reads
    if (kt < qt) STAGEKV(kt + 1, b ^ 1);   // in flight under this tile's compute

    f32x4 sv[4] = {};
#pragma unroll
    for (int kbk = 0; kbk < 4; kbk++) {
#pragma unroll
      for (int t = 0; t < 4; t++) {
        bf16x8 kf = *(const bf16x8*)&Ks[b][(t * 16 + l16) * 128 + (((kbk << 2) + quad) ^ l16) * 8];
        sv[t] = __builtin_amdgcn_mfma_f32_16x16x32_bf16(qf[kbk], kf, sv[t], 0, 0, 0);
      }
    }
    if (kt == qt) {   // diagonal tile masking
#pragma unroll
      for (int t = 0; t < 4; t++) {
        const int key = kbase + t * 16 + l16;
#pragma unroll
        for (int r = 0; r < 4; r++)
          if (key > q0 + quad * 4 + r) sv[t][r] = -1e30f;
      }
    }
    float alpha[4];
#pragma unroll
    for (int r = 0; r < 4; r++) {
      float mx = fmaxf(fmaxf(sv[0][r], sv[1][r]), fmaxf(sv[2][r], sv[3][r]));
#pragma unroll
      for (int off = 8; off; off >>= 1) mx = fmaxf(mx, __shfl_xor(mx, off));
      const float mnew = fmaxf(mrow[r], mx);
      alpha[r] = __builtin_exp2f(mrow[r] - mnew);
      mrow[r] = mnew;
#pragma unroll
      for (int t = 0; t < 4; t++)
        sv[t][r] = __builtin_exp2f(sv[t][r] - mnew);
    }
#pragma unroll
    for (int dt = 0; dt < 8; dt++)
#pragma unroll
      for (int r = 0; r < 4; r++) oacc[dt][r] *= alpha[r];
#pragma unroll
    for (int r = 0; r < 4; r++) lacc[r] *= alpha[r];
    // P: C-layout -> A-layout via wave-private LDS round-trip (no barriers:
    // plds[wave] touched only by this wave; lgkmcnt ordering suffices)
#pragma unroll
    for (int r = 0; r < 4; r++)
#pragma unroll
      for (int t = 0; t < 4; t++)
        plds[wave][quad * 4 + r][t * 16 + l16] = f2bf(sv[t][r]);
    bf16x8 pf0 = *(const bf16x8*)&plds[wave][l16][quad * 8];
    bf16x8 pf1 = *(const bf16x8*)&plds[wave][l16][32 + quad * 8];
    // row-sum of P via ones B-frag: lacc[r] += sum_k P[row][k] (replicated over l16)
    lacc = __builtin_amdgcn_mfma_f32_16x16x32_bf16(pf0, onesf, lacc, 0, 0, 0);
    lacc = __builtin_amdgcn_mfma_f32_16x16x32_bf16(pf1, onesf, lacc, 0, 0, 0);
#pragma unroll
    for (int dt = 0; dt < 8; dt++) {
      const int vrow = (dt * 16 + l16) * 64;
      bf16x8 vf0 = *(const bf16x8*)&Vs[b][vrow + ((quad) ^ (l16 & 7)) * 8];
      oacc[dt] = __builtin_amdgcn_mfma_f32_16x16x32_bf16(pf0, vf0, oacc[dt], 0, 0, 0);
      bf16x8 vf1 = *(const bf16x8*)&Vs[b][vrow + ((4 + quad) ^ (l16 & 7)) * 8];
      oacc[dt] = __builtin_amdgcn_mfma_f32_16x16x32_bf16(pf1, vf1, oacc[dt], 0, 0, 0);
    }
  }
#undef STAGEKV
#pragma unroll
  for (int dt = 0; dt < 8; dt++) {
#pragma unroll
    for (int r = 0; r < 4; r++) {
      const float v = oacc[dt][r] / lacc[r];
      ob[(size_t)(q0 + quad * 4 + r) * ATTN_N + h * HD + dt * 16 + l16] = f2bf(v);
    }
  }
}

extern "C" void kernel_launch(void* const* d_in, const int* in_sizes, int n_in,
                              void* d_out, int out_size, void* d_ws, size_t ws_size,
                              hipStream_t stream) {
  const void* hs_raw   = d_in[0];
  const void* cos_raw  = d_in[1];
  const void* sin_raw  = d_in[2];
  const void* wqkv_raw = d_in[3];
  const void* bqkv_raw = d_in[4];
  const void* wo_raw   = d_in[5];
  unsigned short* ws = (unsigned short*)d_ws;

  unsigned short* R1   = ws;                           // wt_qkv -> q/k/vt bufs -> wt_o
  unsigned short* R2   = R1 + (size_t)QKVN * HIDDEN;   // qkv -> attnb
  unsigned short* hs_c = R2 + (size_t)SEQ * QKVN;
  float* cosf  = (float*)(hs_c + (size_t)SEQ * HIDDEN);
  float* sinf  = cosf + SEQ * 64;
  float* biasf = sinf + SEQ * 64;
  int*   flag  = (int*)(biasf + QKVN);

  unsigned short* wt_qkv = R1;
  unsigned short* qbuf   = R1;
  unsigned short* kbuf   = qbuf + (size_t)NQH * SEQ * HD;
  unsigned short* vtbuf  = kbuf + (size_t)NKVH * SEQ * HD;
  unsigned short* wt_o   = R1;
  unsigned short* qkv    = R2;
  unsigned short* attnb  = R2;

  detect_dtype<<<1, 1, 0, stream>>>((const unsigned short*)hs_raw, flag);
  to_bf16_any<<<(SEQ * HIDDEN / 4 + 255) / 256, 256, 0, stream>>>(hs_raw, hs_c, SEQ * HIDDEN / 4, flag);
  to_f32_any<<<(SEQ * 64 / 4 + 255) / 256, 256, 0, stream>>>(cos_raw, cosf, SEQ * 64 / 4, flag);
  to_f32_any<<<(SEQ * 64 / 4 + 255) / 256, 256, 0, stream>>>(sin_raw, sinf, SEQ * 64 / 4, flag);
  to_f32_any<<<(QKVN / 4 + 255) / 256, 256, 0, stream>>>(bqkv_raw, biasf, QKVN / 4, flag);

  transpose_any<<<dim3(QKVN / 32, HIDDEN / 32), 256, 0, stream>>>(wqkv_raw, wt_qkv, HIDDEN, QKVN, flag);
  gemm_bt<<<dim3(QKVN / 128, SEQ / 128), 256, 0, stream>>>(hs_c, wt_qkv, biasf, qkv, SEQ, QKVN, HIDDEN, nullptr);
  rope_split<<<SEQ, 256, 0, stream>>>(qkv, cosf, sinf, qbuf, kbuf, vtbuf);
  attn_fwd<<<dim3(NQH, SEQ / 64), 256, 0, stream>>>(qbuf, kbuf, vtbuf, attnb);
  transpose_any<<<dim3(ATTN_N / 32, HIDDEN / 32), 256, 0, stream>>>(wo_raw, wt_o, HIDDEN, ATTN_N, flag);
  gemm_bt<<<dim3(ATTN_N / 128, SEQ / 128), 256, 0, stream>>>(attnb, wt_o, nullptr, d_out, SEQ, ATTN_N, HIDDEN, flag);
}

// Round 5
// 493.895 us; speedup vs baseline: 1.0759x; 1.0071x over previous
//
#include <hip/hip_runtime.h>
#include <stdint.h>

#define SEQ    2048
#define HIDDEN 4096
#define NQH    32
#define NKVH   2
#define HD     128
#define QKVN   4608   // (32+4)*128
#define ATTN_N 4096   // 32*128

typedef short bf16x8 __attribute__((ext_vector_type(8)));
typedef float f32x4  __attribute__((ext_vector_type(4)));

#define ASYNC16(gp, lp) __builtin_amdgcn_global_load_lds( \
    (const __attribute__((address_space(1))) void*)(gp),  \
    (__attribute__((address_space(3))) void*)(lp), 16, 0, 0)

__device__ __forceinline__ float bf2f(unsigned short u) {
  union { unsigned int i; float f; } v; v.i = ((unsigned int)u) << 16; return v.f;
}
__device__ __forceinline__ unsigned short f2bf(float f) {
  union { float f; unsigned int i; } v; v.f = f;
  unsigned int r = v.i + 0x7fffu + ((v.i >> 16) & 1u);  // RNE
  return (unsigned short)(r >> 16);
}

// ---- dtype probe: bf16 arrays have sane exponents at every index; fp32 read
// ---- as ushort has uniform-random exponent bits at even indices. flag=1 -> fp32
__global__ void detect_dtype(const unsigned short* __restrict__ hs, int* __restrict__ flag) {
  int bad = 0;
  for (int i = 0; i < 128; i += 2) {
    const int e = (hs[i] >> 7) & 0xFF;
    if (e < 100 || e > 140) bad++;
  }
  *flag = (bad > 16) ? 1 : 0;
}

__global__ void to_bf16_any(const void* __restrict__ in, unsigned short* __restrict__ out,
                            int n4, const int* __restrict__ flag) {
  const int i = blockIdx.x * blockDim.x + threadIdx.x;
  if (i >= n4) return;
  if (*flag) {
    const float4 f = ((const float4*)in)[i];
    ushort4 u; u.x = f2bf(f.x); u.y = f2bf(f.y); u.z = f2bf(f.z); u.w = f2bf(f.w);
    ((ushort4*)out)[i] = u;
  } else {
    ((ushort4*)out)[i] = ((const ushort4*)in)[i];
  }
}

__global__ void to_f32_any(const void* __restrict__ in, float* __restrict__ out,
                           int n4, const int* __restrict__ flag) {
  const int i = blockIdx.x * blockDim.x + threadIdx.x;
  if (i >= n4) return;
  if (*flag) {
    ((float4*)out)[i] = ((const float4*)in)[i];
  } else {
    const ushort4 u = ((const ushort4*)in)[i];
    float4 f; f.x = bf2f(u.x); f.y = bf2f(u.y); f.z = bf2f(u.z); f.w = bf2f(u.w);
    ((float4*)out)[i] = f;
  }
}

// ---- 64x64 transpose + convert: out[c][r] (bf16) = in[r][c]; in is R x C ----
// Read: 64B/thread (4x float4 or 2x 16B bf16). LDS rows padded to 72 ushorts
// (144B = 9x16B: keeps b128 writes aligned). Write-side: lanes differ only in
// output column -> column reads hit 32 distinct banks (conflict-free); 16B
// global stores; the 4 waves cover adjacent 16B row-segments so L2 assembles
// full lines. Replaces 32x32/8B-store version (4x fewer blocks, 2x wider IO).
__global__ __launch_bounds__(256)
void transpose64(const void* __restrict__ in, unsigned short* __restrict__ out,
                 int R, int C, const int* __restrict__ flag) {
  __shared__ __attribute__((aligned(16))) unsigned short t[64][72];
  const int r0 = blockIdx.y * 64, c0 = blockIdx.x * 64;
  const int lr = threadIdx.x >> 2;          // 0..63: input row
  const int lc = (threadIdx.x & 3) << 4;    // 0,16,32,48: input col segment
  bf16x8 v0, v1;
  if (*flag) {
    const float* src = (const float*)in + (size_t)(r0 + lr) * C + c0 + lc;
    const float4 f0 = ((const float4*)src)[0];
    const float4 f1 = ((const float4*)src)[1];
    const float4 f2 = ((const float4*)src)[2];
    const float4 f3 = ((const float4*)src)[3];
    v0[0] = f2bf(f0.x); v0[1] = f2bf(f0.y); v0[2] = f2bf(f0.z); v0[3] = f2bf(f0.w);
    v0[4] = f2bf(f1.x); v0[5] = f2bf(f1.y); v0[6] = f2bf(f1.z); v0[7] = f2bf(f1.w);
    v1[0] = f2bf(f2.x); v1[1] = f2bf(f2.y); v1[2] = f2bf(f2.z); v1[3] = f2bf(f2.w);
    v1[4] = f2bf(f3.x); v1[5] = f2bf(f3.y); v1[6] = f2bf(f3.z); v1[7] = f2bf(f3.w);
  } else {
    const unsigned short* src = (const unsigned short*)in + (size_t)(r0 + lr) * C + c0 + lc;
    v0 = *(const bf16x8*)src;
    v1 = *(const bf16x8*)(src + 8);
  }
  *(bf16x8*)&t[lr][lc]     = v0;
  *(bf16x8*)&t[lr][lc + 8] = v1;
  __syncthreads();
  const int oc = threadIdx.x & 63;          // output row (= input col)
  const int rb = (threadIdx.x >> 6) * 8;    // r-segment base per wave
#pragma unroll
  for (int it = 0; it < 2; ++it) {
    const int rseg = rb + it * 32;
    bf16x8 w;
#pragma unroll
    for (int j = 0; j < 8; j++) w[j] = (short)t[rseg + j][oc];
    *(bf16x8*)(out + (size_t)(c0 + oc) * R + r0 + rseg) = w;
  }
}

// ------------- C = A(MxK) * Bt(NxK)^T (+bias), bf16 in, fp32 acc --------------
// m97 structure, 128x128 tile. ROUND-5: BK=64 as two 32-k sub-tiles staged in
// one barrier-pair (8 ASYNC16/thread) -> halves barrier + vmcnt(0) drain count,
// 32 MFMA/wave per drain (was 16). LDS 32KB (still >=2 blocks/CU; occupancy is
// grid-limited at 2.25 blocks/CU, so no m132-style cliff). Swizzle per half
// unchanged (BANK_CONFLICT=0 measured). Half-1 ds_reads overlap half-0 MFMAs.
__global__ __launch_bounds__(256, 2)
void gemm_bt(const unsigned short* __restrict__ A,
             const unsigned short* __restrict__ Bt,
             const float* __restrict__ bias,
             void* __restrict__ C,
             int M, int N, int K, const int* __restrict__ of32) {
  __shared__ __attribute__((aligned(16))) unsigned short As[2][128 * 32];
  __shared__ __attribute__((aligned(16))) unsigned short Bs[2][128 * 32];
  const int tid  = threadIdx.x;
  const int wave = tid >> 6, lane = tid & 63;
  const int quad = lane >> 4, l16 = lane & 15;
  const int m0 = blockIdx.y * 128, n0 = blockIdx.x * 128;
  const int wm = (wave >> 1) * 64, wn = (wave & 1) * 64;

  // thread t stages row=t/4, swizzled k-chunk g=(t&3)^((row>>1)&3); LDS = t*16B
  const int crow = tid >> 2;
  const int gsw = ((tid & 3) ^ ((crow >> 1) & 3)) << 3;
  const unsigned short* gA = A + (size_t)(m0 + crow) * K + gsw;
  const unsigned short* gB = Bt + (size_t)(n0 + crow) * K + gsw;
  const size_t r64 = (size_t)64 * K;
  const int l8 = tid * 8;

  // frag-read swizzled chunk offset (elements)
  const int cxor = (quad ^ ((l16 >> 1) & 3)) << 3;

  f32x4 acc[4][4] = {};

  for (int k0 = 0; k0 < K; k0 += 64) {
    __syncthreads();                 // prev iter's LDS reads done
    ASYNC16(gA + k0,            &As[0][l8]);
    ASYNC16(gA + r64 + k0,      &As[0][l8 + 2048]);
    ASYNC16(gA + k0 + 32,       &As[1][l8]);
    ASYNC16(gA + r64 + k0 + 32, &As[1][l8 + 2048]);
    ASYNC16(gB + k0,            &Bs[0][l8]);
    ASYNC16(gB + r64 + k0,      &Bs[0][l8 + 2048]);
    ASYNC16(gB + k0 + 32,       &Bs[1][l8]);
    ASYNC16(gB + r64 + k0 + 32, &Bs[1][l8 + 2048]);
    __syncthreads();                 // drains vmcnt: both halves visible
#pragma unroll
    for (int h = 0; h < 2; h++) {
      bf16x8 aF[4], bF[4];
#pragma unroll
      for (int i = 0; i < 4; i++)
        aF[i] = *(const bf16x8*)&As[h][(wm + i * 16 + l16) * 32 + cxor];
#pragma unroll
      for (int j = 0; j < 4; j++)
        bF[j] = *(const bf16x8*)&Bs[h][(wn + j * 16 + l16) * 32 + cxor];
#pragma unroll
      for (int i = 0; i < 4; i++)
#pragma unroll
        for (int j = 0; j < 4; j++)
          acc[i][j] = __builtin_amdgcn_mfma_f32_16x16x32_bf16(aF[i], bF[j], acc[i][j], 0, 0, 0);
    }
  }

  const int wf32 = of32 ? *of32 : 0;
#pragma unroll
  for (int j = 0; j < 4; j++) {
    const int col = n0 + wn + j * 16 + l16;
    const float bv = bias ? bias[col] : 0.0f;
#pragma unroll
    for (int i = 0; i < 4; i++) {
#pragma unroll
      for (int r = 0; r < 4; r++) {
        const int row = m0 + wm + i * 16 + quad * 4 + r;   // C/D: row=quad*4+reg, col=l16
        const float v = acc[i][j][r] + bv;
        const size_t off = (size_t)row * N + col;
        if (wf32) ((float*)C)[off] = v;
        else      ((unsigned short*)C)[off] = f2bf(v);
      }
    }
  }
}

// --------- RoPE (interleaved) + split into Q (scaled), K, V^T buffers ---------
// ROUND-5: vectorized — bf16x8 loads (16B/thread), float4 cos/sin, bf16x8 Q/K
// stores. V (no rope) stays scalar-scattered (1/18 of elements, transposed).
__global__ void rope_split(const unsigned short* __restrict__ qkv,
                           const float* __restrict__ cosb,
                           const float* __restrict__ sinb,
                           unsigned short* __restrict__ qb,
                           unsigned short* __restrict__ kb,
                           unsigned short* __restrict__ vtb) {
  const int s = blockIdx.x;
  const unsigned short* row = qkv + (size_t)s * QKVN;
  const float sc = 0.08838834764831845f * 1.44269504088896341f;  // 1/sqrt(128)*log2(e)
  for (int p8 = threadIdx.x; p8 < QKVN / 8; p8 += blockDim.x) {
    const int col = p8 << 3;          // 8 consecutive elems, within one head
    const int head = col >> 7;
    const int d = col & 127;
    const bf16x8 x = *(const bf16x8*)&row[col];
    if (head >= NQH + NKVH) {         // V: transposed copy, no rope
      const int vh = head - NQH - NKVH;
      unsigned short* vp = vtb + (size_t)vh * HD * SEQ + (size_t)d * SEQ + s;
#pragma unroll
      for (int j = 0; j < 8; j++) vp[(size_t)j * SEQ] = (unsigned short)x[j];
      continue;
    }
    float y[8];
#pragma unroll
    for (int j = 0; j < 8; j++) y[j] = bf2f((unsigned short)x[j]);
    if (d < 64) {
      const float4 c4 = *(const float4*)&cosb[s * 64 + (d >> 1)];
      const float4 s4 = *(const float4*)&sinb[s * 64 + (d >> 1)];
      const float cc[4] = {c4.x, c4.y, c4.z, c4.w};
      const float ss[4] = {s4.x, s4.y, s4.z, s4.w};
#pragma unroll
      for (int q = 0; q < 4; q++) {
        const float x0 = y[2 * q], x1 = y[2 * q + 1];
        y[2 * q]     = x0 * cc[q] - x1 * ss[q];
        y[2 * q + 1] = x1 * cc[q] + x0 * ss[q];
      }
    }
    bf16x8 o;
    if (head < NQH) {
#pragma unroll
      for (int j = 0; j < 8; j++) o[j] = (short)f2bf(y[j] * sc);
      *(bf16x8*)&qb[(size_t)head * SEQ * HD + (size_t)s * HD + d] = o;
    } else {
#pragma unroll
      for (int j = 0; j < 8; j++) o[j] = (short)f2bf(y[j]);
      *(bf16x8*)&kb[(size_t)(head - NQH) * SEQ * HD + (size_t)s * HD + d] = o;
    }
  }
}

// ------------------- causal flash attention, bf16 MFMA ------------------------
// grid (32 heads, 32 q-tiles of 64 rows), heavy-first. 4 waves/block, 16 rows/wave.
// Double-buffered K/V, single barrier per K-tile (round-4 structure; measured
// neutral vs 4-barrier/3-block version — kept for its latency headroom).
// plds wave-private (no barriers). Row-sums of P via ones-B-frag MFMA.
__global__ __launch_bounds__(256, 2)
void attn_fwd(const unsigned short* __restrict__ qb,
              const unsigned short* __restrict__ kb,
              const unsigned short* __restrict__ vtb,
              unsigned short* __restrict__ ob) {
  const int h = blockIdx.x;
  const int qt = 31 - (int)blockIdx.y;            // heavy-first scheduling
  const int tid = threadIdx.x;
  const int wave = tid >> 6, lane = tid & 63;
  const int quad = lane >> 4, l16 = lane & 15;
  const int q0 = qt * 64 + wave * 16;
  const unsigned short* qh  = qb  + (size_t)h * SEQ * HD;
  const unsigned short* kh  = kb  + (size_t)(h >> 4) * SEQ * HD;
  const unsigned short* vth = vtb + (size_t)(h >> 4) * HD * SEQ;

  __shared__ __attribute__((aligned(16))) unsigned short Ks[2][64 * 128];  // [key][d], chunk-swizzled
  __shared__ __attribute__((aligned(16))) unsigned short Vs[2][128 * 64];  // [d][key], chunk-swizzled
  __shared__ __attribute__((aligned(16))) unsigned short plds[4][16][80];  // wave-private

  bf16x8 qf[4];
#pragma unroll
  for (int kbk = 0; kbk < 4; kbk++)   // A-frag: A[m=l16][k=quad*8+j]
    qf[kbk] = *(const bf16x8*)&qh[(size_t)(q0 + l16) * HD + kbk * 32 + quad * 8];

  bf16x8 onesf;
#pragma unroll
  for (int i = 0; i < 8; i++) onesf[i] = (short)0x3F80;   // bf16 1.0

  f32x4 oacc[8] = {};
  f32x4 lacc = {};
  float mrow[4] = {-1e30f, -1e30f, -1e30f, -1e30f};

  // stage tile kt_ into buffer bsel: 8 global_load_lds per thread
#define STAGEKV(kt_, bsel) do {                                                  \
    const int kb_ = (kt_) * 64;                                                  \
    _Pragma("unroll")                                                            \
    for (int c = 0; c < 4; c++) {                                                \
      const int j = c * 256 + tid;                                               \
      const int key = j >> 4;                                                    \
      const int g = (j & 15) ^ (key & 15);                                       \
      ASYNC16(kh + (size_t)(kb_ + key) * HD + g * 8, &Ks[bsel][0] + j * 8);      \
    }                                                                            \
    _Pragma("unroll")                                                            \
    for (int c = 0; c < 4; c++) {                                                \
      const int j = c * 256 + tid;                                               \
      const int d = j >> 3;                                                      \
      const int g = (j & 7) ^ (d & 7);                                           \
      ASYNC16(vth + (size_t)d * SEQ + kb_ + g * 8, &Vs[bsel][0] + j * 8);        \
    }                                                                            \
  } while (0)

  STAGEKV(0, 0);

  for (int kt = 0; kt <= qt; kt++) {
    const int b = kt & 1;
    const int kbase = kt * 64;
    __syncthreads();                   // drains vmcnt: tile kt visible to all;
                                       // all waves done with iter kt-1 reads
    if (kt < qt) STAGEKV(kt + 1, b ^ 1);   // in flight under this tile's compute

    f32x4 sv[4] = {};
#pragma unroll
    for (int kbk = 0; kbk < 4; kbk++) {
#pragma unroll
      for (int t = 0; t < 4; t++) {
        bf16x8 kf = *(const bf16x8*)&Ks[b][(t * 16 + l16) * 128 + (((kbk << 2) + quad) ^ l16) * 8];
        sv[t] = __builtin_amdgcn_mfma_f32_16x16x32_bf16(qf[kbk], kf, sv[t], 0, 0, 0);
      }
    }
    if (kt == qt) {   // diagonal tile masking
#pragma unroll
      for (int t = 0; t < 4; t++) {
        const int key = kbase + t * 16 + l16;
#pragma unroll
        for (int r = 0; r < 4; r++)
          if (key > q0 + quad * 4 + r) sv[t][r] = -1e30f;
      }
    }
    float alpha[4];
#pragma unroll
    for (int r = 0; r < 4; r++) {
      float mx = fmaxf(fmaxf(sv[0][r], sv[1][r]), fmaxf(sv[2][r], sv[3][r]));
#pragma unroll
      for (int off = 8; off; off >>= 1) mx = fmaxf(mx, __shfl_xor(mx, off));
      const float mnew = fmaxf(mrow[r], mx);
      alpha[r] = __builtin_exp2f(mrow[r] - mnew);
      mrow[r] = mnew;
#pragma unroll
      for (int t = 0; t < 4; t++)
        sv[t][r] = __builtin_exp2f(sv[t][r] - mnew);
    }
#pragma unroll
    for (int dt = 0; dt < 8; dt++)
#pragma unroll
      for (int r = 0; r < 4; r++) oacc[dt][r] *= alpha[r];
#pragma unroll
    for (int r = 0; r < 4; r++) lacc[r] *= alpha[r];
    // P: C-layout -> A-layout via wave-private LDS round-trip (no barriers)
#pragma unroll
    for (int r = 0; r < 4; r++)
#pragma unroll
      for (int t = 0; t < 4; t++)
        plds[wave][quad * 4 + r][t * 16 + l16] = f2bf(sv[t][r]);
    bf16x8 pf0 = *(const bf16x8*)&plds[wave][l16][quad * 8];
    bf16x8 pf1 = *(const bf16x8*)&plds[wave][l16][32 + quad * 8];
    // row-sum of P via ones B-frag: lacc[r] += sum_k P[row][k] (replicated over l16)
    lacc = __builtin_amdgcn_mfma_f32_16x16x32_bf16(pf0, onesf, lacc, 0, 0, 0);
    lacc = __builtin_amdgcn_mfma_f32_16x16x32_bf16(pf1, onesf, lacc, 0, 0, 0);
#pragma unroll
    for (int dt = 0; dt < 8; dt++) {
      const int vrow = (dt * 16 + l16) * 64;
      bf16x8 vf0 = *(const bf16x8*)&Vs[b][vrow + ((quad) ^ (l16 & 7)) * 8];
      oacc[dt] = __builtin_amdgcn_mfma_f32_16x16x32_bf16(pf0, vf0, oacc[dt], 0, 0, 0);
      bf16x8 vf1 = *(const bf16x8*)&Vs[b][vrow + ((4 + quad) ^ (l16 & 7)) * 8];
      oacc[dt] = __builtin_amdgcn_mfma_f32_16x16x32_bf16(pf1, vf1, oacc[dt], 0, 0, 0);
    }
  }
#undef STAGEKV
#pragma unroll
  for (int dt = 0; dt < 8; dt++) {
#pragma unroll
    for (int r = 0; r < 4; r++) {
      const float v = oacc[dt][r] / lacc[r];
      ob[(size_t)(q0 + quad * 4 + r) * ATTN_N + h * HD + dt * 16 + l16] = f2bf(v);
    }
  }
}

extern "C" void kernel_launch(void* const* d_in, const int* in_sizes, int n_in,
                              void* d_out, int out_size, void* d_ws, size_t ws_size,
                              hipStream_t stream) {
  const void* hs_raw   = d_in[0];
  const void* cos_raw  = d_in[1];
  const void* sin_raw  = d_in[2];
  const void* wqkv_raw = d_in[3];
  const void* bqkv_raw = d_in[4];
  const void* wo_raw   = d_in[5];
  unsigned short* ws = (unsigned short*)d_ws;

  unsigned short* R1   = ws;                           // wt_qkv -> q/k/vt bufs -> wt_o
  unsigned short* R2   = R1 + (size_t)QKVN * HIDDEN;   // qkv -> attnb
  unsigned short* hs_c = R2 + (size_t)SEQ * QKVN;
  float* cosf  = (float*)(hs_c + (size_t)SEQ * HIDDEN);
  float* sinf  = cosf + SEQ * 64;
  float* biasf = sinf + SEQ * 64;
  int*   flag  = (int*)(biasf + QKVN);

  unsigned short* wt_qkv = R1;
  unsigned short* qbuf   = R1;
  unsigned short* kbuf   = qbuf + (size_t)NQH * SEQ * HD;
  unsigned short* vtbuf  = kbuf + (size_t)NKVH * SEQ * HD;
  unsigned short* wt_o   = R1;
  unsigned short* qkv    = R2;
  unsigned short* attnb  = R2;

  detect_dtype<<<1, 1, 0, stream>>>((const unsigned short*)hs_raw, flag);
  to_bf16_any<<<(SEQ * HIDDEN / 4 + 255) / 256, 256, 0, stream>>>(hs_raw, hs_c, SEQ * HIDDEN / 4, flag);
  to_f32_any<<<(SEQ * 64 / 4 + 255) / 256, 256, 0, stream>>>(cos_raw, cosf, SEQ * 64 / 4, flag);
  to_f32_any<<<(SEQ * 64 / 4 + 255) / 256, 256, 0, stream>>>(sin_raw, sinf, SEQ * 64 / 4, flag);
  to_f32_any<<<(QKVN / 4 + 255) / 256, 256, 0, stream>>>(bqkv_raw, biasf, QKVN / 4, flag);

  transpose64<<<dim3(QKVN / 64, HIDDEN / 64), 256, 0, stream>>>(wqkv_raw, wt_qkv, HIDDEN, QKVN, flag);
  gemm_bt<<<dim3(QKVN / 128, SEQ / 128), 256, 0, stream>>>(hs_c, wt_qkv, biasf, qkv, SEQ, QKVN, HIDDEN, nullptr);
  rope_split<<<SEQ, 256, 0, stream>>>(qkv, cosf, sinf, qbuf, kbuf, vtbuf);
  attn_fwd<<<dim3(NQH, SEQ / 64), 256, 0, stream>>>(qbuf, kbuf, vtbuf, attnb);
  transpose64<<<dim3(ATTN_N / 64, HIDDEN / 64), 256, 0, stream>>>(wo_raw, wt_o, HIDDEN, ATTN_N, flag);
  gemm_bt<<<dim3(ATTN_N / 128, SEQ / 128), 256, 0, stream>>>(attnb, wt_o, nullptr, d_out, SEQ, ATTN_N, HIDDEN, flag);
}